// Round 2
// baseline (80.510 us; speedup 1.0000x reference)
//
#include <hip/hip_runtime.h>

// UVFA_text: B=256, M2=100, SV=OV=32, R=128, L=12, V=1000, E=64
// out[b,p] = sum_k relu(h2[p,k]) * u[k] + bs3.w
//   h2[p,k] = relu(base_s + Ws1_pos[p]) @ Ws2[:,k] + bs2[k]
//   w = obj_mlp(b) * lstm_h(b);  u = Ws3 @ w

#define B_   256
#define M2_  100
#define R_   128
#define L_   12
#define E_   64
#define G4_  512

#define X8(OP)  OP(0) OP(1) OP(2) OP(3) OP(4) OP(5) OP(6) OP(7)
#define X12(OP) X8(OP) OP(8) OP(9) OP(10) OP(11)
#define X32(OP) X12(OP) OP(12) OP(13) OP(14) OP(15) OP(16) OP(17) OP(18) OP(19) \
                OP(20) OP(21) OP(22) OP(23) OP(24) OP(25) OP(26) OP(27) \
                OP(28) OP(29) OP(30) OP(31)

__device__ __forceinline__ float sigf(float x) { return 1.f / (1.f + expf(-x)); }

__global__ __launch_bounds__(512, 2) void uvfa_kernel(
    const int* __restrict__ state, const int* __restrict__ obj, const int* __restrict__ text,
    const float* __restrict__ Ws1, const float* __restrict__ bs1,
    const float* __restrict__ Ws2, const float* __restrict__ bs2,
    const float* __restrict__ Ws3, const float* __restrict__ bs3,
    const float* __restrict__ Wo1, const float* __restrict__ bo1,
    const float* __restrict__ Wo2, const float* __restrict__ bo2,
    const float* __restrict__ Wo3, const float* __restrict__ bo3,
    const float* __restrict__ emb, const float* __restrict__ Wih,
    const float* __restrict__ Whh, const float* __restrict__ b_lstm,
    float* __restrict__ out)
{
    const int b   = blockIdx.x;
    const int tid = threadIdx.x;

    // big: phase 1 = xw[12][512] (6144) + xemb[12][64] (768); phase 2 = h1[100][128] (12800)
    __shared__ __align__(16) float big[12800];          // 51.2 KB
    __shared__ float gbuf[G4_];                          // LSTM gates; later 'part'
    __shared__ float hbuf[R_];
    __shared__ float redw[8][M2_];                       // per-wave k-partials
    __shared__ float tmp[R_], tmp2[R_], wbuf[R_], ubuf[R_], bsbuf[R_];
    __shared__ int   idx[M2_], tids[L_];
    __shared__ float c0s;

    float* xw   = big;          // [12][512]
    float* xemb = big + 6144;   // [12][64]

    // ---------------- text ids + embeddings ----------------
    if (tid < L_) tids[tid] = text[b * L_ + tid];
    if (tid < R_) hbuf[tid] = 0.f;
    __syncthreads();
    for (int i = tid; i < L_ * E_; i += G4_)
        xemb[i] = emb[tids[i >> 6] * E_ + (i & 63)];
    __syncthreads();

    // ---------------- xw[t][col] = b_lstm + x_t @ Wih ----------------
    {
        float bl = b_lstm[tid];
        #define DECL_A(i) float a##i = bl;
        X12(DECL_A)
        for (int e = 0; e < E_; ++e) {
            float we = Wih[e * G4_ + tid];
            #define FMA_A(i) a##i = fmaf(xemb[(i) * E_ + e], we, a##i);
            X12(FMA_A)
        }
        #define ST_A(i) xw[(i) * G4_ + tid] = a##i;
        X12(ST_A)
    }

    // ---------------- Whh column tid -> 32 named float4 (forced registers) ----------------
    #define DECL_W(i) float4 w##i;
    X32(DECL_W)
    #define LD_W(i) w##i.x = Whh[(4*(i)+0)*G4_ + tid]; w##i.y = Whh[(4*(i)+1)*G4_ + tid]; \
                    w##i.z = Whh[(4*(i)+2)*G4_ + tid]; w##i.w = Whh[(4*(i)+3)*G4_ + tid];
    X32(LD_W)
    __syncthreads();   // xw + hbuf ready

    // ---------------- LSTM recurrence ----------------
    float cst = 0.f;
    {
        const float4* hb4 = reinterpret_cast<const float4*>(hbuf);
        for (int t = 0; t < L_; ++t) {
            float a0 = xw[t * G4_ + tid], a1 = 0.f, a2 = 0.f, a3 = 0.f;
            #define FMA_W(i) { float4 h4 = hb4[i]; \
                a0 = fmaf(h4.x, w##i.x, a0); a1 = fmaf(h4.y, w##i.y, a1); \
                a2 = fmaf(h4.z, w##i.z, a2); a3 = fmaf(h4.w, w##i.w, a3); }
            X32(FMA_W)
            gbuf[tid] = (a0 + a1) + (a2 + a3);
            __syncthreads();
            if (tid < R_) {
                float gi = gbuf[tid], gf = gbuf[R_ + tid], gg = gbuf[2*R_ + tid], go = gbuf[3*R_ + tid];
                cst = sigf(gf) * cst + sigf(gi) * tanhf(gg);
                hbuf[tid] = sigf(go) * tanhf(cst);
            }
            __syncthreads();
        }
    }

    // ---------------- object MLP (k=tid&127, qq=tid>>7 mapping) ----------------
    float* part = gbuf;
    const int k = tid & 127, qq = tid >> 7;
    if (tid < M2_) idx[tid] = obj[b * M2_ + tid];
    __syncthreads();
    {
        float acc = 0.f;
        #pragma unroll 5
        for (int c = qq * 25; c < qq * 25 + 25; ++c)
            acc += Wo1[(c * 32 + idx[c]) * R_ + k];
        part[qq * R_ + k] = acc;
    }
    __syncthreads();
    if (tid < R_) tmp[tid] = fmaxf(bo1[tid] + part[tid] + part[R_+tid] + part[2*R_+tid] + part[3*R_+tid], 0.f);
    __syncthreads();
    {
        float s0 = 0.f, s1 = 0.f, s2 = 0.f, s3 = 0.f;
        #pragma unroll
        for (int j = 0; j < 32; j += 4) {
            int j0 = qq * 32 + j;
            s0 = fmaf(tmp[j0+0], Wo2[(j0+0)*R_ + k], s0);
            s1 = fmaf(tmp[j0+1], Wo2[(j0+1)*R_ + k], s1);
            s2 = fmaf(tmp[j0+2], Wo2[(j0+2)*R_ + k], s2);
            s3 = fmaf(tmp[j0+3], Wo2[(j0+3)*R_ + k], s3);
        }
        part[qq * R_ + k] = (s0+s1)+(s2+s3);
    }
    __syncthreads();
    if (tid < R_) tmp2[tid] = fmaxf(bo2[tid] + part[tid] + part[R_+tid] + part[2*R_+tid] + part[3*R_+tid], 0.f);
    __syncthreads();
    {
        float s0 = 0.f, s1 = 0.f, s2 = 0.f, s3 = 0.f;
        #pragma unroll
        for (int j = 0; j < 32; j += 4) {
            int j0 = qq * 32 + j;
            s0 = fmaf(tmp2[j0+0], Wo3[(j0+0)*R_ + k], s0);
            s1 = fmaf(tmp2[j0+1], Wo3[(j0+1)*R_ + k], s1);
            s2 = fmaf(tmp2[j0+2], Wo3[(j0+2)*R_ + k], s2);
            s3 = fmaf(tmp2[j0+3], Wo3[(j0+3)*R_ + k], s3);
        }
        part[qq * R_ + k] = (s0+s1)+(s2+s3);
    }
    __syncthreads();
    if (tid < R_)
        wbuf[tid] = (bo3[tid] + part[tid] + part[R_+tid] + part[2*R_+tid] + part[3*R_+tid]) * hbuf[tid];
    __syncthreads();

    // ---------------- u = Ws3 @ w ; c0 = bs3 . w ----------------
    {
        float s0 = 0.f, s1 = 0.f, s2 = 0.f, s3 = 0.f;
        const float4* w4 = reinterpret_cast<const float4*>(&Ws3[k * R_ + qq * 32]);
        #pragma unroll
        for (int jj = 0; jj < 8; ++jj) {
            float4 v = w4[jj];
            int j0 = qq * 32 + jj * 4;
            s0 = fmaf(v.x, wbuf[j0+0], s0);
            s1 = fmaf(v.y, wbuf[j0+1], s1);
            s2 = fmaf(v.z, wbuf[j0+2], s2);
            s3 = fmaf(v.w, wbuf[j0+3], s3);
        }
        part[qq * R_ + k] = (s0+s1)+(s2+s3);
    }
    if (tid == G4_ - 1) {
        float s = 0.f;
        for (int j = 0; j < R_; ++j) s += bs3[j] * wbuf[j];
        c0s = s;
    }
    __syncthreads();
    if (tid < R_) ubuf[tid] = part[tid] + part[R_+tid] + part[2*R_+tid] + part[3*R_+tid];

    // ---------------- base_s = bs1 + gather(Ws1) ----------------
    if (tid < M2_) idx[tid] = state[b * M2_ + tid];
    __syncthreads();
    {
        float acc = 0.f;
        #pragma unroll 5
        for (int c = qq * 25; c < qq * 25 + 25; ++c)
            acc += Ws1[(c * 33 + idx[c]) * R_ + k];
        part[qq * R_ + k] = acc;
    }
    __syncthreads();
    if (tid < R_) bsbuf[tid] = bs1[tid] + part[tid] + part[R_+tid] + part[2*R_+tid] + part[3*R_+tid];

    // ---------------- phase-A weights: Ws2 quarter-column, pre-rotated ----------------
    const int k2 = tid >> 2, q2 = tid & 3, wid = tid >> 6;
    #define DECL_C(i) float4 wc##i;
    X8(DECL_C)
    #define LD_C(i) { int m = ((i) + 2*q2) & 7; int j0 = q2*32 + m*4; \
        wc##i.x = Ws2[(j0+0)*R_ + k2]; wc##i.y = Ws2[(j0+1)*R_ + k2]; \
        wc##i.z = Ws2[(j0+2)*R_ + k2]; wc##i.w = Ws2[(j0+3)*R_ + k2]; }
    X8(LD_C)
    __syncthreads();   // bsbuf + ubuf ready

    // ---------------- h1[p][k] = relu(bsbuf[k] + Ws1_pos[p][k]) for all 100 p ----------------
    for (int i = tid; i < M2_ * R_; i += G4_)
        big[i] = fmaxf(bsbuf[i & 127] + Ws1[((i >> 7) * 33 + 32) * R_ + (i & 127)], 0.f);
    __syncthreads();

    // ---------------- phase A: barrier-free 100x128x128 ----------------
    const float uk   = ubuf[k2];
    const float bs2k = bs2[k2];
    const float4* h1f4 = reinterpret_cast<const float4*>(big);
    #pragma unroll 2
    for (int p = 0; p < M2_; ++p) {
        const float4* rowp = h1f4 + p * 32 + q2 * 8;
        float s0 = 0.f, s1 = 0.f, s2 = 0.f, s3 = 0.f;
        #define FMA_C(i) { float4 h4 = rowp[(((i) + 2*q2) & 7)]; \
            s0 = fmaf(h4.x, wc##i.x, s0); s1 = fmaf(h4.y, wc##i.y, s1); \
            s2 = fmaf(h4.z, wc##i.z, s2); s3 = fmaf(h4.w, wc##i.w, s3); }
        X8(FMA_C)
        float s = (s0 + s1) + (s2 + s3);
        s += __shfl_xor(s, 1, 64);
        s += __shfl_xor(s, 2, 64);          // quad combined: full h2[p][k2] in all 4 lanes
        float val = fmaxf(s + bs2k, 0.f) * uk;
        val += __shfl_down(val, 32, 64);
        val += __shfl_down(val, 16, 64);
        val += __shfl_down(val, 8, 64);
        val += __shfl_down(val, 4, 64);     // lane0: sum over the wave's 16 k's
        if ((tid & 63) == 0) redw[wid][p] = val;
    }
    __syncthreads();

    // ---------------- phase B: combine 8 wave-partials ----------------
    if (tid < M2_) {
        float o = c0s;
        #pragma unroll
        for (int w = 0; w < 8; ++w) o += redw[w][tid];
        out[b * M2_ + tid] = o;
    }
}

extern "C" void kernel_launch(void* const* d_in, const int* in_sizes, int n_in,
                              void* d_out, int out_size, void* d_ws, size_t ws_size,
                              hipStream_t stream) {
    const int*   state  = (const int*)d_in[0];
    const int*   obj    = (const int*)d_in[1];
    const int*   text   = (const int*)d_in[2];
    const float* Ws1    = (const float*)d_in[3];
    const float* bs1    = (const float*)d_in[4];
    const float* Ws2    = (const float*)d_in[5];
    const float* bs2    = (const float*)d_in[6];
    const float* Ws3    = (const float*)d_in[7];
    const float* bs3    = (const float*)d_in[8];
    const float* Wo1    = (const float*)d_in[9];
    const float* bo1    = (const float*)d_in[10];
    const float* Wo2    = (const float*)d_in[11];
    const float* bo2    = (const float*)d_in[12];
    const float* Wo3    = (const float*)d_in[13];
    const float* bo3    = (const float*)d_in[14];
    const float* emb    = (const float*)d_in[15];
    const float* Wih    = (const float*)d_in[16];
    const float* Whh    = (const float*)d_in[17];
    const float* b_lstm = (const float*)d_in[18];
    float* out = (float*)d_out;

    hipLaunchKernelGGL(uvfa_kernel, dim3(B_), dim3(G4_), 0, stream,
                       state, obj, text, Ws1, bs1, Ws2, bs2, Ws3, bs3,
                       Wo1, bo1, Wo2, bo2, Wo3, bo3, emb, Wih, Whh, b_lstm, out);
}

// Round 3
// 73.114 us; speedup vs baseline: 1.1011x; 1.1011x over previous
//
#include <hip/hip_runtime.h>

// UVFA_text: B=256, M2=100, SV=OV=32, R=128, L=12, V=1000, E=64
// out[b,p] = sum_k relu(h2[p,k]) * u[k] + bs3.w
//   h2[p,k] = relu(base_s + Ws1_pos[p]) @ Ws2[:,k] + bs2[k]
//   base_s  = bs1 + sum_c Ws1[c*33+state[b,c]]
//   w = obj_mlp(b) * lstm_h(b);  u = Ws3 @ w
// Block = 1024 threads (16 waves, 4/SIMD). Per-thread weight state <= 64 floats.

#define B_   256
#define M2_  100
#define R_   128
#define L_   12
#define E_   64
#define NT   1024

#define X6(OP)  OP(0) OP(1) OP(2) OP(3) OP(4) OP(5)
#define X8(OP)  OP(0) OP(1) OP(2) OP(3) OP(4) OP(5) OP(6) OP(7)
#define X16(OP) X8(OP) OP(8) OP(9) OP(10) OP(11) OP(12) OP(13) OP(14) OP(15)

__device__ __forceinline__ float sigf(float x) { return 1.f / (1.f + expf(-x)); }

__global__ __launch_bounds__(NT, 4) void uvfa_kernel(
    const int* __restrict__ state, const int* __restrict__ obj, const int* __restrict__ text,
    const float* __restrict__ Ws1, const float* __restrict__ bs1,
    const float* __restrict__ Ws2, const float* __restrict__ bs2,
    const float* __restrict__ Ws3, const float* __restrict__ bs3,
    const float* __restrict__ Wo1, const float* __restrict__ bo1,
    const float* __restrict__ Wo2, const float* __restrict__ bo2,
    const float* __restrict__ Wo3, const float* __restrict__ bo3,
    const float* __restrict__ emb, const float* __restrict__ Wih,
    const float* __restrict__ Whh, const float* __restrict__ b_lstm,
    float* __restrict__ out)
{
    const int b   = blockIdx.x;
    const int tid = threadIdx.x;

    // big: phase 1 = xw[12][512] (6144) + xemb[12][64]; phase 2 = h1[100][128]
    __shared__ __align__(16) float big[12800];   // 51.2 KB
    __shared__ float part[NT];                   // gates / partial sums
    __shared__ float hbuf[R_];
    __shared__ float redw[16][50];
    __shared__ float tmp[R_], tmp2[R_], wbuf[R_], ubuf[R_], bsbuf[R_];
    __shared__ int   idx_o[M2_], idx_s[M2_], tids[L_];
    __shared__ float c0s;

    float* xw   = big;          // [12][512]
    float* xemb = big + 6144;   // [12][64]

    // ---------- P1: ids, init (spread across thread groups) ----------
    if (tid < L_) tids[tid] = text[b * L_ + tid];
    if (tid >= 128 && tid < 128 + M2_) idx_o[tid - 128] = obj[b * M2_ + tid - 128];
    if (tid >= 256 && tid < 256 + M2_) idx_s[tid - 256] = state[b * M2_ + tid - 256];
    if (tid < R_) hbuf[tid] = 0.f;
    __syncthreads();
    if (tid < L_ * E_) xemb[tid] = emb[tids[tid >> 6] * E_ + (tid & 63)];
    __syncthreads();

    // ---------- P2: xw[t][col] = b_lstm[col] + x_t @ Wih (thread = (t-half, col)) ----------
    {
        const int col = tid & 511, th = tid >> 9;   // th: t in [6*th, 6*th+6)
        float bl = b_lstm[col];
        #define DA(i) float a##i = bl;
        X6(DA)
        const float* xe = xemb + (th * 6) * E_;
        for (int e = 0; e < E_; ++e) {
            float we = Wih[e * 512 + col];
            #define FA(i) a##i = fmaf(xe[(i) * E_ + e], we, a##i);
            X6(FA)
        }
        #define SA(i) xw[(th * 6 + (i)) * 512 + col] = a##i;
        X6(SA)
    }

    // ---------- Whh half-column per thread: 16 float4 = 64 regs ----------
    const int colW = tid >> 1, half = tid & 1;
    #define DW(i) float4 w##i;
    X16(DW)
    #define LW(i) { int r = 64 * half + 4 * (i); \
        w##i.x = Whh[(r + 0) * 512 + colW]; w##i.y = Whh[(r + 1) * 512 + colW]; \
        w##i.z = Whh[(r + 2) * 512 + colW]; w##i.w = Whh[(r + 3) * 512 + colW]; }
    X16(LW)
    __syncthreads();   // xw + hbuf ready

    // ---------- P3: LSTM recurrence (pair-split columns) ----------
    float cst = 0.f;
    {
        const float4* hb4 = reinterpret_cast<const float4*>(hbuf) + 16 * half;
        #define FW(i) { float4 h4 = hb4[i]; \
            s0 = fmaf(h4.x, w##i.x, s0); s1 = fmaf(h4.y, w##i.y, s1); \
            s2 = fmaf(h4.z, w##i.z, s2); s3 = fmaf(h4.w, w##i.w, s3); }
        for (int t = 0; t < L_; ++t) {
            float s0 = half ? 0.f : xw[t * 512 + colW];
            float s1 = 0.f, s2 = 0.f, s3 = 0.f;
            X16(FW)
            float s = (s0 + s1) + (s2 + s3);
            s += __shfl_xor(s, 1, 64);          // combine j-halves of this column
            if (!half) part[colW] = s;
            __syncthreads();
            if (tid < R_) {
                float gi = part[tid], gf = part[R_ + tid], gg = part[2 * R_ + tid], go = part[3 * R_ + tid];
                cst = sigf(gf) * cst + sigf(gi) * tanhf(gg);
                hbuf[tid] = sigf(go) * tanhf(cst);
            }
            __syncthreads();
        }
    }

    // ---------- P4: object MLP ----------
    const int k = tid & 127, qq = tid >> 7;   // qq 0..7
    {
        float acc = 0.f;
        int c0i = qq * 13, c1i = c0i + 13 < M2_ ? c0i + 13 : M2_;
        for (int c = c0i; c < c1i; ++c)
            acc += Wo1[(c * 32 + idx_o[c]) * R_ + k];
        part[qq * R_ + k] = acc;
    }
    __syncthreads();
    if (tid < R_) {
        float a = bo1[tid];
        #pragma unroll
        for (int q = 0; q < 8; ++q) a += part[q * R_ + tid];
        tmp[tid] = fmaxf(a, 0.f);
    }
    __syncthreads();
    if (tid < 512) {
        float s0 = 0.f, s1 = 0.f, s2 = 0.f, s3 = 0.f;
        int j0 = qq * 32;
        #pragma unroll
        for (int j = 0; j < 32; j += 4) {
            s0 = fmaf(tmp[j0 + j + 0], Wo2[(j0 + j + 0) * R_ + k], s0);
            s1 = fmaf(tmp[j0 + j + 1], Wo2[(j0 + j + 1) * R_ + k], s1);
            s2 = fmaf(tmp[j0 + j + 2], Wo2[(j0 + j + 2) * R_ + k], s2);
            s3 = fmaf(tmp[j0 + j + 3], Wo2[(j0 + j + 3) * R_ + k], s3);
        }
        part[qq * R_ + k] = (s0 + s1) + (s2 + s3);
    }
    __syncthreads();
    if (tid < R_)
        tmp2[tid] = fmaxf(bo2[tid] + part[tid] + part[R_ + tid] + part[2 * R_ + tid] + part[3 * R_ + tid], 0.f);
    __syncthreads();
    if (tid < 512) {
        float s0 = 0.f, s1 = 0.f, s2 = 0.f, s3 = 0.f;
        int j0 = qq * 32;
        #pragma unroll
        for (int j = 0; j < 32; j += 4) {
            s0 = fmaf(tmp2[j0 + j + 0], Wo3[(j0 + j + 0) * R_ + k], s0);
            s1 = fmaf(tmp2[j0 + j + 1], Wo3[(j0 + j + 1) * R_ + k], s1);
            s2 = fmaf(tmp2[j0 + j + 2], Wo3[(j0 + j + 2) * R_ + k], s2);
            s3 = fmaf(tmp2[j0 + j + 3], Wo3[(j0 + j + 3) * R_ + k], s3);
        }
        part[qq * R_ + k] = (s0 + s1) + (s2 + s3);
    }
    __syncthreads();
    if (tid < R_)
        wbuf[tid] = (bo3[tid] + part[tid] + part[R_ + tid] + part[2 * R_ + tid] + part[3 * R_ + tid]) * hbuf[tid];
    __syncthreads();

    // ---------- P5: u = Ws3 @ w (tid<512); c0 = bs3 . w (last wave) ----------
    if (tid < 512) {
        float s0 = 0.f, s1 = 0.f, s2 = 0.f, s3 = 0.f;
        const float4* w4 = reinterpret_cast<const float4*>(&Ws3[k * R_ + qq * 32]);
        #pragma unroll
        for (int jj = 0; jj < 8; ++jj) {
            float4 v = w4[jj];
            int j0 = qq * 32 + jj * 4;
            s0 = fmaf(v.x, wbuf[j0 + 0], s0);
            s1 = fmaf(v.y, wbuf[j0 + 1], s1);
            s2 = fmaf(v.z, wbuf[j0 + 2], s2);
            s3 = fmaf(v.w, wbuf[j0 + 3], s3);
        }
        part[qq * R_ + k] = (s0 + s1) + (s2 + s3);
    }
    if (tid >= 960) {
        int j = tid - 960;
        float s = bs3[j] * wbuf[j] + bs3[j + 64] * wbuf[j + 64];
        s += __shfl_down(s, 32, 64);
        s += __shfl_down(s, 16, 64);
        s += __shfl_down(s, 8, 64);
        s += __shfl_down(s, 4, 64);
        s += __shfl_down(s, 2, 64);
        s += __shfl_down(s, 1, 64);
        if (j == 0) c0s = s;
    }
    __syncthreads();
    if (tid < R_) ubuf[tid] = part[tid] + part[R_ + tid] + part[2 * R_ + tid] + part[3 * R_ + tid];

    // ---------- P6: base_s gather ----------
    {
        float acc = 0.f;
        int c0i = qq * 13, c1i = c0i + 13 < M2_ ? c0i + 13 : M2_;
        for (int c = c0i; c < c1i; ++c)
            acc += Ws1[(c * 33 + idx_s[c]) * R_ + k];
        part[qq * R_ + k] = acc;
    }
    __syncthreads();
    if (tid < R_) {
        float a = bs1[tid];
        #pragma unroll
        for (int q = 0; q < 8; ++q) a += part[q * R_ + tid];
        bsbuf[tid] = a;
    }

    // ---------- Ws2 quarter-column, pre-rotated: 8 float4 = 32 regs ----------
    const int k2 = (tid >> 2) & 127, q2 = tid & 3;
    #define DC(i) float4 wc##i;
    X8(DC)
    #define LC(i) { int m = ((i) + 2 * q2) & 7; int j0 = q2 * 32 + m * 4; \
        wc##i.x = Ws2[(j0 + 0) * R_ + k2]; wc##i.y = Ws2[(j0 + 1) * R_ + k2]; \
        wc##i.z = Ws2[(j0 + 2) * R_ + k2]; wc##i.w = Ws2[(j0 + 3) * R_ + k2]; }
    X8(LC)
    __syncthreads();   // bsbuf + ubuf ready; xw dead

    // ---------- h1[p][k] = relu(bsbuf[k] + Ws1_pos[p][k]) ----------
    for (int i = tid; i < M2_ * R_; i += NT)
        big[i] = fmaxf(bsbuf[i & 127] + Ws1[((i >> 7) * 33 + 32) * R_ + (i & 127)], 0.f);
    __syncthreads();

    // ---------- main: 100x128x128, 2 positions in flight, barrier-free ----------
    const int   pp   = tid >> 9;       // position parity
    const int   wid  = tid >> 6;       // wave id 0..15
    const float uk   = ubuf[k2];
    const float bs2k = bs2[k2];
    const float4* h1f4 = reinterpret_cast<const float4*>(big);
    #define FC(i) { float4 h4 = rowp[(((i) + 2 * q2) & 7)]; \
        s0 = fmaf(h4.x, wc##i.x, s0); s1 = fmaf(h4.y, wc##i.y, s1); \
        s2 = fmaf(h4.z, wc##i.z, s2); s3 = fmaf(h4.w, wc##i.w, s3); }
    #pragma unroll 2
    for (int it = 0; it < 50; ++it) {
        int p = 2 * it + pp;
        const float4* rowp = h1f4 + p * 32 + q2 * 8;
        float s0 = 0.f, s1 = 0.f, s2 = 0.f, s3 = 0.f;
        X8(FC)
        float s = (s0 + s1) + (s2 + s3);
        s += __shfl_xor(s, 1, 64);
        s += __shfl_xor(s, 2, 64);          // quad combined: full h2[p][k2]
        float val = fmaxf(s + bs2k, 0.f) * uk;
        val += __shfl_down(val, 32, 64);
        val += __shfl_down(val, 16, 64);
        val += __shfl_down(val, 8, 64);
        val += __shfl_down(val, 4, 64);     // lane0: one lane per quad -> 16 k's
        if ((tid & 63) == 0) redw[wid][it] = val;
    }
    __syncthreads();

    // ---------- combine 8 wave-partials per position ----------
    if (tid < M2_) {
        int it = tid >> 1, pg = tid & 1;
        float o = c0s;
        #pragma unroll
        for (int w = 0; w < 8; ++w) o += redw[pg * 8 + w][it];
        out[b * M2_ + tid] = o;
    }
}

extern "C" void kernel_launch(void* const* d_in, const int* in_sizes, int n_in,
                              void* d_out, int out_size, void* d_ws, size_t ws_size,
                              hipStream_t stream) {
    const int*   state  = (const int*)d_in[0];
    const int*   obj    = (const int*)d_in[1];
    const int*   text   = (const int*)d_in[2];
    const float* Ws1    = (const float*)d_in[3];
    const float* bs1    = (const float*)d_in[4];
    const float* Ws2    = (const float*)d_in[5];
    const float* bs2    = (const float*)d_in[6];
    const float* Ws3    = (const float*)d_in[7];
    const float* bs3    = (const float*)d_in[8];
    const float* Wo1    = (const float*)d_in[9];
    const float* bo1    = (const float*)d_in[10];
    const float* Wo2    = (const float*)d_in[11];
    const float* bo2    = (const float*)d_in[12];
    const float* Wo3    = (const float*)d_in[13];
    const float* bo3    = (const float*)d_in[14];
    const float* emb    = (const float*)d_in[15];
    const float* Wih    = (const float*)d_in[16];
    const float* Whh    = (const float*)d_in[17];
    const float* b_lstm = (const float*)d_in[18];
    float* out = (float*)d_out;

    hipLaunchKernelGGL(uvfa_kernel, dim3(B_), dim3(NT), 0, stream,
                       state, obj, text, Ws1, bs1, Ws2, bs2, Ws3, bs3,
                       Wo1, bo1, Wo2, bo2, Wo3, bo3, emb, Wih, Whh, b_lstm, out);
}